// Round 5
// baseline (3489.397 us; speedup 1.0000x reference)
//
#include <hip/hip_runtime.h>
#include <hip/hip_bf16.h>

// GATv2 x2 on MI355X. N=100000, E=3200000, D=128, H=1, C1=16, C2=32.
// d_in floats are FLOAT32 (round-4 falsified bf16: NaN from garbage reads).
// d_out: FLOAT32, 3E = 9.6M floats = [edges(2E) | alpha2(E)].
// ZERO d_ws usage. d_out scratch plan (phase-disjoint, floats):
//  A=[0,E):    e  (score1 -> ex1 -> alpha1 -> score2 -> ex2, slot-in-place)
//  B=[E,2E):   xl1/xr1 as f32 (N*16 each = 3.2M floats exactly);
//              after agg1 they die -> xl2/xr2 as bf16 (N*32 each = 6.4M bf16);
//              after edge2 those die -> first N floats become den2 (re-zeroed)
//  C=[2E,3E):  out1 (N*16 f32) | m1 (N) | den1 (N) | m2 (N), zeroed once;
//              all dead before div_kernel overwrites C with alpha2.
//  edges passthrough overwrites [0,2E) LAST.

#define NN 100000
#define EE 3200000
#define DD 128
#define CC1 16
#define CC2 32
#define NEG_SLOPE 0.2f

typedef __hip_bfloat16 bf16;

__device__ __forceinline__ float b2f(bf16 v) { return __bfloat162float(v); }

// load 8 consecutive bf16 -> 8 floats (one 16B load); internal scratch only
__device__ __forceinline__ void ld8bf(const bf16* p, float* f) {
    uint4 u = *(const uint4*)p;
    const unsigned w[4] = {u.x, u.y, u.z, u.w};
#pragma unroll
    for (int i = 0; i < 4; i++) {
        f[2 * i]     = __uint_as_float(w[i] << 16);
        f[2 * i + 1] = __uint_as_float(w[i] & 0xffff0000u);
    }
}

// Order-preserving float<->uint encoding for atomicMax segment-max.
// Any finite float encodes > 0, so the 0-init never wins for a connected node.
__device__ __forceinline__ unsigned enc_f(float x) {
    unsigned b = __float_as_uint(x);
    return (b & 0x80000000u) ? ~b : (b | 0x80000000u);
}
__device__ __forceinline__ float dec_f(unsigned u) {
    unsigned b = (u & 0x80000000u) ? (u & 0x7fffffffu) : ~u;
    return __uint_as_float(b);
}

// ---------- Layer-1 node transform: xl1 = x@Wl1+bl1, xr1 = x@Wr1+br1 (f32 out) ----------
// block 256 = 8 nodes x 32 cols (16 Wl + 16 Wr). Grid NN/8 = 12500 exact.
__global__ void lin1_kernel(const float* __restrict__ x,
                            const float* __restrict__ Wl, const float* __restrict__ bl,
                            const float* __restrict__ Wr, const float* __restrict__ br,
                            float* __restrict__ xl1, float* __restrict__ xr1) {
    __shared__ float Ws[DD][32];   // col<16: Wl, col>=16: Wr
    __shared__ float xs[8][DD];
    const int t = threadIdx.x;
    for (int i = t; i < DD * CC1; i += 256) {
        int k = i >> 4, c = i & 15;
        Ws[k][c]      = Wl[i];
        Ws[k][c + 16] = Wr[i];
    }
    const int node0 = blockIdx.x * 8;
    for (int i = t; i < 8 * DD; i += 256) {
        int n = i >> 7, k = i & 127;
        xs[n][k] = x[(node0 + n) * DD + k];
    }
    __syncthreads();
    const int n = t >> 5, c = t & 31;
    const int node = node0 + n;
    float acc = 0.f;
#pragma unroll 16
    for (int k = 0; k < DD; k++) acc += xs[n][k] * Ws[k][c];
    if (c < 16) xl1[node * CC1 + c]        = acc + bl[c];
    else        xr1[node * CC1 + (c - 16)] = acc + br[c - 16];
}

// ---------- Layer-1 edge scores + segment max ----------
__global__ void edge1_kernel(const int* __restrict__ edges,
                             const float* __restrict__ ew,
                             const float* __restrict__ xl1, const float* __restrict__ xr1,
                             const float* __restrict__ We1, const float* __restrict__ att1,
                             float* __restrict__ e1, unsigned* __restrict__ m1) {
    __shared__ float Wes[CC1], atts[CC1];
    if (threadIdx.x < CC1) {
        Wes[threadIdx.x]  = We1[threadIdx.x];
        atts[threadIdx.x] = att1[threadIdx.x];
    }
    __syncthreads();
    const int e = blockIdx.x * 256 + threadIdx.x;   // grid covers E exactly
    const int s = edges[e], d = edges[EE + e];
    const float w = ew[e];
    const float4* a4 = (const float4*)(xl1 + s * CC1);
    const float4* b4 = (const float4*)(xr1 + d * CC1);
    float acc = 0.f;
#pragma unroll
    for (int q = 0; q < 4; q++) {
        float4 av = a4[q], bv = b4[q];
        float sv[4] = {av.x + bv.x, av.y + bv.y, av.z + bv.z, av.w + bv.w};
#pragma unroll
        for (int j = 0; j < 4; j++) {
            float v = sv[j] + w * Wes[q * 4 + j];
            v = v > 0.f ? v : NEG_SLOPE * v;
            acc += v * atts[q * 4 + j];
        }
    }
    e1[e] = acc;
    atomicMax(&m1[d], enc_f(acc));
}

// ---------- softmax numerator: e = exp(e - m[dst]); denom += e (in-place) ----------
__global__ void softmax_num_kernel(const int* __restrict__ dst,
                                   const unsigned* __restrict__ m,
                                   float* __restrict__ e, float* __restrict__ denom) {
    const int i = blockIdx.x * 256 + threadIdx.x;
    const int d = dst[i];
    const float v = __expf(e[i] - dec_f(m[d]));
    e[i] = v;
    atomicAdd(&denom[d], v);
}

// ---------- Layer-1 agg: alpha1 = ex/den (in place); out1[dst] += alpha1 * xl1[src] ----------
__global__ void agg1_kernel(const int* __restrict__ edges,
                            float* __restrict__ e, const float* __restrict__ denom,
                            const float* __restrict__ xl1,
                            float* __restrict__ out1) {
    const int i = blockIdx.x * 256 + threadIdx.x;
    const int s = edges[i], d = edges[EE + i];
    const float a = e[i] / (denom[d] + 1e-16f);
    e[i] = a;                              // alpha1, same slot
    const float4* x4 = (const float4*)(xl1 + s * CC1);
    float* o = out1 + d * CC1;
#pragma unroll
    for (int q = 0; q < 4; q++) {
        float4 v = x4[q];
        atomicAdd(o + q * 4 + 0, a * v.x);
        atomicAdd(o + q * 4 + 1, a * v.y);
        atomicAdd(o + q * 4 + 2, a * v.z);
        atomicAdd(o + q * 4 + 3, a * v.w);
    }
}

// ---------- Layer-2 node transform: h = relu(out1+b1); xl2/xr2 = h@W2 (bf16 out, internal) ----------
// block 256 = 4 nodes x 64 cols. Grid NN/4 = 25000 exact. xl2/xr2 overwrite xl1/xr1 (dead).
__global__ void lin2_kernel(const float* __restrict__ out1, const float* __restrict__ b1,
                            const float* __restrict__ Wl2, const float* __restrict__ bl2,
                            const float* __restrict__ Wr2, const float* __restrict__ br2,
                            bf16* __restrict__ xl2, bf16* __restrict__ xr2) {
    __shared__ float Ws[CC1][64];  // col<32: Wl2, col>=32: Wr2
    __shared__ float hs[4][CC1];
    const int t = threadIdx.x;
    for (int i = t; i < CC1 * CC2; i += 256) {
        int k = i >> 5, c = i & 31;
        Ws[k][c]      = Wl2[i];
        Ws[k][c + 32] = Wr2[i];
    }
    const int node0 = blockIdx.x * 4;
    if (t < 64) {
        int n = t >> 4, k = t & 15;
        float v = out1[(node0 + n) * CC1 + k] + b1[k];
        hs[n][k] = v > 0.f ? v : 0.f;
    }
    __syncthreads();
    const int n = t >> 6, c = t & 63;
    const int node = node0 + n;
    float acc = 0.f;
#pragma unroll
    for (int k = 0; k < CC1; k++) acc += hs[n][k] * Ws[k][c];
    if (c < 32) xl2[node * CC2 + c]        = __float2bfloat16(acc + bl2[c]);
    else        xr2[node * CC2 + (c - 32)] = __float2bfloat16(acc + br2[c - 32]);
}

// ---------- Layer-2 edge scores + segment max (edge feature = alpha1, in-place over e) ----------
__global__ void edge2_kernel(const int* __restrict__ edges,
                             float* __restrict__ e,     // in: alpha1, out: score2
                             const bf16* __restrict__ xl2, const bf16* __restrict__ xr2,
                             const float* __restrict__ We2, const float* __restrict__ att2,
                             unsigned* __restrict__ m2) {
    __shared__ float Wes[CC2], atts[CC2];
    if (threadIdx.x < CC2) {
        Wes[threadIdx.x]  = We2[threadIdx.x];
        atts[threadIdx.x] = att2[threadIdx.x];
    }
    __syncthreads();
    const int i = blockIdx.x * 256 + threadIdx.x;
    const int s = edges[i], d = edges[EE + i];
    const float w = e[i];
    float a[CC2], b[CC2];
#pragma unroll
    for (int q = 0; q < 4; q++) {
        ld8bf(xl2 + s * CC2 + 8 * q, a + 8 * q);
        ld8bf(xr2 + d * CC2 + 8 * q, b + 8 * q);
    }
    float acc = 0.f;
#pragma unroll
    for (int c = 0; c < CC2; c++) {
        float v = a[c] + b[c] + w * Wes[c];
        v = v > 0.f ? v : NEG_SLOPE * v;
        acc += v * atts[c];
    }
    e[i] = acc;
    atomicMax(&m2[d], enc_f(acc));
}

// ---------- alpha2 = ex2/den2 -> floats [2E,3E) (accumulators there are dead) ----------
__global__ void div_kernel(const int* __restrict__ dst,
                           const float* __restrict__ e, const float* __restrict__ den2,
                           float* __restrict__ out) {
    const int i = blockIdx.x * 256 + threadIdx.x;
    const int d = dst[i];
    out[2 * EE + i] = e[i] / (den2[d] + 1e-16f);
}

// ---------- edges passthrough -> floats [0,2E), LAST ----------
__global__ void edges_kernel(const int* __restrict__ edges, float* __restrict__ out) {
    const int i = blockIdx.x * 256 + threadIdx.x;   // grid covers 2E
    out[i] = (float)edges[i];
}

extern "C" void kernel_launch(void* const* d_in, const int* in_sizes, int n_in,
                              void* d_out, int out_size, void* d_ws, size_t ws_size,
                              hipStream_t stream) {
    const float* x    = (const float*)d_in[0];
    const int*  edges = (const int*)d_in[1];
    const float* ew   = (const float*)d_in[2];
    const float* Wl1  = (const float*)d_in[3];
    const float* bl1  = (const float*)d_in[4];
    const float* Wr1  = (const float*)d_in[5];
    const float* br1  = (const float*)d_in[6];
    const float* We1  = (const float*)d_in[7];
    const float* att1 = (const float*)d_in[8];
    const float* b1   = (const float*)d_in[9];
    const float* Wl2  = (const float*)d_in[10];
    const float* bl2  = (const float*)d_in[11];
    const float* Wr2  = (const float*)d_in[12];
    const float* br2  = (const float*)d_in[13];
    const float* We2  = (const float*)d_in[14];
    const float* att2 = (const float*)d_in[15];
    float* out = (float*)d_out;

    // Region A: e scratch
    float* e = out;                                   // [0,E)
    // Region B: layer-1 features f32, then layer-2 features bf16, then den2
    float* xl1 = out + EE;                            // N*16 f32
    float* xr1 = xl1 + NN * CC1;                      // N*16 f32
    bf16*  nf2 = (bf16*)(out + EE);                   // after agg1: N*64 bf16
    bf16*  xl2 = nf2;                                 // N*32
    bf16*  xr2 = nf2 + NN * CC2;                      // N*32
    float* den2 = out + EE;                           // N floats (after edge2)
    // Region C: accumulators (dead before div overwrites C with alpha2)
    float*    out1 = out + 2 * EE;                    // N*16
    unsigned* m1   = (unsigned*)(out1 + NN * CC1);    // N
    float*    den1 = (float*)(m1 + NN);               // N
    unsigned* m2   = (unsigned*)(den1 + NN);          // N

    const int* dst = edges + EE;
    const int EG = EE / 256;   // 12500

    // zero out1+m1+den1+m2 = N*19 floats (7.6 MB) in region C
    hipMemsetAsync(out1, 0, (size_t)NN * 19 * sizeof(float), stream);

    lin1_kernel<<<NN / 8, 256, 0, stream>>>(x, Wl1, bl1, Wr1, br1, xl1, xr1);
    edge1_kernel<<<EG, 256, 0, stream>>>(edges, ew, xl1, xr1, We1, att1, e, m1);
    softmax_num_kernel<<<EG, 256, 0, stream>>>(dst, m1, e, den1);
    agg1_kernel<<<EG, 256, 0, stream>>>(edges, e, den1, xl1, out1);
    lin2_kernel<<<NN / 4, 256, 0, stream>>>(out1, b1, Wl2, bl2, Wr2, br2, xl2, xr2);
    edge2_kernel<<<EG, 256, 0, stream>>>(edges, e, xl2, xr2, We2, att2, m2);
    // layer-2 features now dead: reuse start of region B for den2
    hipMemsetAsync(den2, 0, (size_t)NN * sizeof(float), stream);
    softmax_num_kernel<<<EG, 256, 0, stream>>>(dst, m2, e, den2);
    div_kernel<<<EG, 256, 0, stream>>>(dst, e, den2, out);
    edges_kernel<<<2 * EG, 256, 0, stream>>>(edges, out);
}

// Round 7
// 1295.626 us; speedup vs baseline: 2.6932x; 2.6932x over previous
//
#include <hip/hip_runtime.h>
#include <hip/hip_bf16.h>

// GATv2 x2 on MI355X. N=100000, E=3200000, D=128, H=1, C1=16, C2=32.
// Inputs f32; d_out f32, 3E floats = [edges(2E) | alpha2(E)].
// Round-5: agg1 scatter-atomics (51.2M f32, 1.6GB WRITE) = 75% of runtime ->
// replaced by dst-CSR + gather node1 (zero f32 atomics). Round-6 aborted on a
// layout overflow (xr2 ran 1.6MB past d_out); this round's layout is exact:
//
//  A [0,E):    e      score1 -> score2 -> ex2 (slot-in-place)
//  R [E,2E):   csr (E ints; dead after node1)
//              -> xl2/xr2 (N*64 bf16 = exactly E floats; dead after edge2)
//              -> m2 (N u32) | den2 (N f32) at R base (memset after edge2)
//  C [2E,3E):  off(N+4 int) m1(N f32) den1(N f32) cnt(N int)
//              xl1(N*16 bf16) xr1(N*16 bf16) out1(N*16 bf16) = 3,000,004 fl
//              -- all dead before final_kernel writes alpha2 over C.
//  edges passthrough overwrites [0,2E) LAST.

#define NN 100000
#define EE 3200000
#define DD 128
#define CC1 16
#define CC2 32
#define NEG_SLOPE 0.2f

typedef __hip_bfloat16 bf16;

__device__ __forceinline__ float b2f(bf16 v) { return __bfloat162float(v); }

// load 8 consecutive bf16 -> 8 floats (one 16B load); bases verified 16B-aligned
__device__ __forceinline__ void ld8bf(const bf16* p, float* f) {
    uint4 u = *(const uint4*)p;
    const unsigned w[4] = {u.x, u.y, u.z, u.w};
#pragma unroll
    for (int i = 0; i < 4; i++) {
        f[2 * i]     = __uint_as_float(w[i] << 16);
        f[2 * i + 1] = __uint_as_float(w[i] & 0xffff0000u);
    }
}

// Order-preserving float<->uint encode for atomicMax (0-init == -inf for finite).
__device__ __forceinline__ unsigned enc_f(float x) {
    unsigned b = __float_as_uint(x);
    return (b & 0x80000000u) ? ~b : (b | 0x80000000u);
}
__device__ __forceinline__ float dec_f(unsigned u) {
    unsigned b = (u & 0x80000000u) ? (u & 0x7fffffffu) : ~u;
    return __uint_as_float(b);
}

// ---------- Layer-1 node transform: xl1/xr1 = x@W + b (bf16 out) ----------
__global__ void lin1_kernel(const float* __restrict__ x,
                            const float* __restrict__ Wl, const float* __restrict__ bl,
                            const float* __restrict__ Wr, const float* __restrict__ br,
                            bf16* __restrict__ xl1, bf16* __restrict__ xr1) {
    __shared__ float Ws[DD][32];   // col<16: Wl, col>=16: Wr
    __shared__ float xs[8][DD];
    const int t = threadIdx.x;
    for (int i = t; i < DD * CC1; i += 256) {
        int k = i >> 4, c = i & 15;
        Ws[k][c]      = Wl[i];
        Ws[k][c + 16] = Wr[i];
    }
    const int node0 = blockIdx.x * 8;
    for (int i = t; i < 8 * DD; i += 256) {
        int n = i >> 7, k = i & 127;
        xs[n][k] = x[(node0 + n) * DD + k];
    }
    __syncthreads();
    const int n = t >> 5, c = t & 31;
    const int node = node0 + n;
    float acc = 0.f;
#pragma unroll 16
    for (int k = 0; k < DD; k++) acc += xs[n][k] * Ws[k][c];
    if (c < 16) xl1[node * CC1 + c]        = __float2bfloat16(acc + bl[c]);
    else        xr1[node * CC1 + (c - 16)] = __float2bfloat16(acc + br[c - 16]);
}

// ---------- Layer-1 edge scores + fused dst-histogram ----------
__global__ void edge1_kernel(const int* __restrict__ edges,
                             const float* __restrict__ ew,
                             const bf16* __restrict__ xl1, const bf16* __restrict__ xr1,
                             const float* __restrict__ We1, const float* __restrict__ att1,
                             float* __restrict__ e1, int* __restrict__ cnt) {
    __shared__ float Wes[CC1], atts[CC1];
    if (threadIdx.x < CC1) {
        Wes[threadIdx.x]  = We1[threadIdx.x];
        atts[threadIdx.x] = att1[threadIdx.x];
    }
    __syncthreads();
    const int e = blockIdx.x * 256 + threadIdx.x;   // grid covers E exactly
    const int s = edges[e], d = edges[EE + e];
    const float w = ew[e];
    float a[CC1], b[CC1];
    ld8bf(xl1 + s * CC1, a); ld8bf(xl1 + s * CC1 + 8, a + 8);
    ld8bf(xr1 + d * CC1, b); ld8bf(xr1 + d * CC1 + 8, b + 8);
    float acc = 0.f;
#pragma unroll
    for (int c = 0; c < CC1; c++) {
        float v = a[c] + b[c] + w * Wes[c];
        v = v > 0.f ? v : NEG_SLOPE * v;
        acc += v * atts[c];
    }
    e1[e] = acc;
    atomicAdd(&cnt[d], 1);
}

// ---------- exclusive prefix scan of cnt -> off[N+1] (single block, 1024 thr) ----------
__global__ void scan_kernel(const int* __restrict__ cnt, int* __restrict__ off) {
    __shared__ int part[1024];
    const int t = threadIdx.x;
    const int chunk = (NN + 1023) / 1024;           // 98
    const int beg = t * chunk;
    const int end = min(beg + chunk, NN);
    int s = 0;
    for (int i = beg; i < end; i++) s += cnt[i];
    part[t] = s;
    __syncthreads();
    for (int o = 1; o < 1024; o <<= 1) {            // Hillis-Steele inclusive scan
        int v = (t >= o) ? part[t - o] : 0;
        __syncthreads();
        part[t] += v;
        __syncthreads();
    }
    int run = (t > 0) ? part[t - 1] : 0;            // exclusive prefix of this chunk
    for (int i = beg; i < end; i++) { off[i] = run; run += cnt[i]; }
    if (t == 1023) off[NN] = part[1023];
}

// ---------- scatter edge ids into CSR order (cnt used as countdown cursor) ----------
__global__ void scatter_kernel(const int* __restrict__ edges,
                               const int* __restrict__ off, int* __restrict__ cnt,
                               int* __restrict__ csr) {
    const int i = blockIdx.x * 256 + threadIdx.x;
    const int d = edges[EE + i];
    const int r = atomicSub(&cnt[d], 1);            // r in [1..deg]
    csr[off[d] + r - 1] = i;
}

// ---------- per-node online softmax + aggregation (16 channel-lanes per node) ----------
__global__ void node1_kernel(const int* __restrict__ off, const int* __restrict__ csr,
                             const int* __restrict__ edges,
                             const float* __restrict__ e1, const bf16* __restrict__ xl1,
                             float* __restrict__ m1, float* __restrict__ den1,
                             bf16* __restrict__ out1) {
    const int t = blockIdx.x * 256 + threadIdx.x;   // grid covers N*16 exactly
    const int n = t >> 4, c = t & 15;
    const int beg = off[n], end = off[n + 1];
    float m = -3.0e38f, l = 0.f, acc = 0.f;
    for (int j = beg; j < end; j++) {
        const int eid = csr[j];
        const float s = e1[eid];
        const int src = edges[eid];
        const float xv = b2f(xl1[src * CC1 + c]);
        if (s > m) { const float r = __expf(m - s); l *= r; acc *= r; m = s; }
        const float p = __expf(s - m);
        l += p; acc += p * xv;
    }
    out1[n * CC1 + c] = __float2bfloat16(l > 0.f ? acc / l : 0.f);
    if (c == 0) { m1[n] = m; den1[n] = l; }
}

// ---------- Layer-2 node transform: h = relu(out1+b1); xl2/xr2 = h@W2 (bf16) ----------
__global__ void lin2_kernel(const bf16* __restrict__ out1, const float* __restrict__ b1,
                            const float* __restrict__ Wl2, const float* __restrict__ bl2,
                            const float* __restrict__ Wr2, const float* __restrict__ br2,
                            bf16* __restrict__ xl2, bf16* __restrict__ xr2) {
    __shared__ float Ws[CC1][64];  // col<32: Wl2, col>=32: Wr2
    __shared__ float hs[4][CC1];
    const int t = threadIdx.x;
    for (int i = t; i < CC1 * CC2; i += 256) {
        int k = i >> 5, c = i & 31;
        Ws[k][c]      = Wl2[i];
        Ws[k][c + 32] = Wr2[i];
    }
    const int node0 = blockIdx.x * 4;
    if (t < 64) {
        int n = t >> 4, k = t & 15;
        float v = b2f(out1[(node0 + n) * CC1 + k]) + b1[k];
        hs[n][k] = v > 0.f ? v : 0.f;
    }
    __syncthreads();
    const int n = t >> 6, c = t & 63;
    const int node = node0 + n;
    float acc = 0.f;
#pragma unroll
    for (int k = 0; k < CC1; k++) acc += hs[n][k] * Ws[k][c];
    if (c < 32) xl2[node * CC2 + c]        = __float2bfloat16(acc + bl2[c]);
    else        xr2[node * CC2 + (c - 32)] = __float2bfloat16(acc + br2[c - 32]);
}

// ---------- Layer-2 edge scores; alpha1 inline from m1/den1 (e in-place) ----------
__global__ void edge2_kernel(const int* __restrict__ edges,
                             float* __restrict__ e,     // in: score1, out: score2
                             const float* __restrict__ m1, const float* __restrict__ den1,
                             const bf16* __restrict__ xl2, const bf16* __restrict__ xr2,
                             const float* __restrict__ We2, const float* __restrict__ att2) {
    __shared__ float Wes[CC2], atts[CC2];
    if (threadIdx.x < CC2) {
        Wes[threadIdx.x]  = We2[threadIdx.x];
        atts[threadIdx.x] = att2[threadIdx.x];
    }
    __syncthreads();
    const int i = blockIdx.x * 256 + threadIdx.x;
    const int s = edges[i], d = edges[EE + i];
    const float w = __expf(e[i] - m1[d]) / (den1[d] + 1e-16f);   // alpha1, inline
    float a[CC2], b[CC2];
#pragma unroll
    for (int q = 0; q < 4; q++) {
        ld8bf(xl2 + s * CC2 + 8 * q, a + 8 * q);
        ld8bf(xr2 + d * CC2 + 8 * q, b + 8 * q);
    }
    float acc = 0.f;
#pragma unroll
    for (int c = 0; c < CC2; c++) {
        float v = a[c] + b[c] + w * Wes[c];
        v = v > 0.f ? v : NEG_SLOPE * v;
        acc += v * atts[c];
    }
    e[i] = acc;
}

// ---------- Layer-2 segment max (per-edge int atomics; m2 in dead-R, 0-init) ----------
__global__ void max2_kernel(const int* __restrict__ dst, const float* __restrict__ e2,
                            unsigned* __restrict__ m2) {
    const int i = blockIdx.x * 256 + threadIdx.x;
    atomicMax(&m2[dst[i]], enc_f(e2[i]));
}

// ---------- Layer-2 numerator: e = exp(e - m2[dst]); den2 += e ----------
__global__ void num2_kernel(const int* __restrict__ dst,
                            const unsigned* __restrict__ m2,
                            float* __restrict__ e, float* __restrict__ den2) {
    const int i = blockIdx.x * 256 + threadIdx.x;
    const int d = dst[i];
    const float v = __expf(e[i] - dec_f(m2[d]));
    e[i] = v;
    atomicAdd(&den2[d], v);
}

// ---------- alpha2 -> floats [2E,3E) (all C scratch dead; reads only A and R) ----------
__global__ void final_kernel(const int* __restrict__ dst,
                             const float* __restrict__ e,
                             const float* __restrict__ den2,
                             float* __restrict__ out) {
    const int i = blockIdx.x * 256 + threadIdx.x;
    const int d = dst[i];
    out[2 * EE + i] = e[i] / (den2[d] + 1e-16f);
}

// ---------- edges passthrough -> floats [0,2E), LAST ----------
__global__ void edges_kernel(const int* __restrict__ edges, float* __restrict__ out) {
    const int i = blockIdx.x * 256 + threadIdx.x;   // grid covers 2E
    out[i] = (float)edges[i];
}

extern "C" void kernel_launch(void* const* d_in, const int* in_sizes, int n_in,
                              void* d_out, int out_size, void* d_ws, size_t ws_size,
                              hipStream_t stream) {
    const float* x    = (const float*)d_in[0];
    const int*  edges = (const int*)d_in[1];
    const float* ew   = (const float*)d_in[2];
    const float* Wl1  = (const float*)d_in[3];
    const float* bl1  = (const float*)d_in[4];
    const float* Wr1  = (const float*)d_in[5];
    const float* br1  = (const float*)d_in[6];
    const float* We1  = (const float*)d_in[7];
    const float* att1 = (const float*)d_in[8];
    const float* b1   = (const float*)d_in[9];
    const float* Wl2  = (const float*)d_in[10];
    const float* bl2  = (const float*)d_in[11];
    const float* Wr2  = (const float*)d_in[12];
    const float* br2  = (const float*)d_in[13];
    const float* We2  = (const float*)d_in[14];
    const float* att2 = (const float*)d_in[15];
    float* out = (float*)d_out;

    // ---- Region A ----
    float* e = out;                                   // [0, E)
    // ---- Region R [E,2E): csr -> xl2/xr2 -> m2/den2 ----
    int*      csr  = (int*)(out + EE);                // E ints (exact fill)
    bf16*     xl2  = (bf16*)(out + EE);               // N*32 bf16 -> [E, E+1.6M) fl
    bf16*     xr2  = xl2 + NN * CC2;                  // N*32 bf16 -> [E+1.6M, 2E) fl
    unsigned* m2   = (unsigned*)(out + EE);           // N (after xl2/xr2 die)
    float*    den2 = (float*)(out + EE) + NN;         // N
    // ---- Region C [2E,3E): off|m1|den1|cnt|xl1|xr1|out1 = 3,000,004 fl ----
    int*   off  = (int*)(out + 2 * EE);               // N+1 (padded to N+4)
    float* m1   = (float*)(off + NN + 4);             // N
    float* den1 = m1 + NN;                            // N
    int*   cnt  = (int*)(den1 + NN);                  // N
    bf16*  xl1  = (bf16*)(cnt + NN);                  // N*16 bf16 (16B-aligned)
    bf16*  xr1  = xl1 + NN * CC1;                     // N*16 bf16
    bf16*  out1 = xr1 + NN * CC1;                     // N*16 bf16, ends 9,200,004 <= 9.6M

    const int* dst = edges + EE;
    const int EG = EE / 256;                          // 12500

    hipMemsetAsync(cnt, 0, (size_t)NN * sizeof(int), stream);

    lin1_kernel   <<<NN / 8, 256, 0, stream>>>(x, Wl1, bl1, Wr1, br1, xl1, xr1);
    edge1_kernel  <<<EG, 256, 0, stream>>>(edges, ew, xl1, xr1, We1, att1, e, cnt);
    scan_kernel   <<<1, 1024, 0, stream>>>(cnt, off);
    scatter_kernel<<<EG, 256, 0, stream>>>(edges, off, cnt, csr);
    node1_kernel  <<<NN * 16 / 256, 256, 0, stream>>>(off, csr, edges, e, xl1, m1, den1, out1);
    lin2_kernel   <<<NN / 4, 256, 0, stream>>>(out1, b1, Wl2, bl2, Wr2, br2, xl2, xr2);
    edge2_kernel  <<<EG, 256, 0, stream>>>(edges, e, m1, den1, xl2, xr2, We2, att2);
    // xl2/xr2 dead: reuse R base for m2/den2
    hipMemsetAsync(m2, 0, (size_t)2 * NN * sizeof(float), stream);
    max2_kernel   <<<EG, 256, 0, stream>>>(dst, e, m2);
    num2_kernel   <<<EG, 256, 0, stream>>>(dst, m2, e, den2);
    final_kernel  <<<EG, 256, 0, stream>>>(dst, e, den2, out);
    edges_kernel  <<<2 * EG, 256, 0, stream>>>(edges, out);
}